// Round 1
// baseline (1228.439 us; speedup 1.0000x reference)
//
#include <hip/hip_runtime.h>
#include <math.h>

// Problem constants
#define T_SEQ 2048
#define NH 12
#define DH 64
#define CDIM 768
#define BSZ 2
#define MTOT (BSZ*T_SEQ)          // 4096
#define SCALE 0.125f              // 1/sqrt(64)
#define LOG10000_32 0.2878231366242557f  // ln(10000)/32

// ---------------------------------------------------------------------------
// Kernel 1: QKV projection.  O[m][n] = sum_c x[m][c] * W[n][c]
// written to q/k/v in (b, h, t, d) layout.  BM=128, BN=64(=D), BK=32.
// 256 threads, 8x4 per thread.  LDS k-major with stride padding (132/68:
// stride%32==4 -> conflict-spread, stride%4==0 -> float4-aligned).
// ---------------------------------------------------------------------------
__global__ __launch_bounds__(256) void qkv_proj_kernel(
    const float* __restrict__ x, const float* __restrict__ Wq,
    const float* __restrict__ Wk, const float* __restrict__ Wv,
    float* __restrict__ q, float* __restrict__ k, float* __restrict__ v)
{
    const int which = blockIdx.z;
    const float* W = which == 0 ? Wq : (which == 1 ? Wk : Wv);
    float* out = which == 0 ? q : (which == 1 ? k : v);

    __shared__ float As[32][132];
    __shared__ float Bs[32][68];

    const int tid = threadIdx.x;
    const int tx = tid & 15;      // -> n (4 cols each)
    const int ty = tid >> 4;      // -> m (8 rows each)
    const int m0 = blockIdx.x * 128;
    const int h  = blockIdx.y;    // n0 = h*64

    float acc[8][4];
    #pragma unroll
    for (int i = 0; i < 8; i++)
        #pragma unroll
        for (int j = 0; j < 4; j++) acc[i][j] = 0.f;

    for (int c0 = 0; c0 < CDIM; c0 += 32) {
        #pragma unroll
        for (int u = 0; u < 4; u++) {              // A tile 128x32
            int f = tid + 256 * u;                 // 0..1023 float4s
            int row = f >> 3, cs = f & 7;
            float4 val = *(const float4*)(x + (size_t)(m0 + row) * CDIM + c0 + cs * 4);
            As[cs*4+0][row] = val.x; As[cs*4+1][row] = val.y;
            As[cs*4+2][row] = val.z; As[cs*4+3][row] = val.w;
        }
        #pragma unroll
        for (int u = 0; u < 2; u++) {              // B tile 64x32
            int f = tid + 256 * u;                 // 0..511
            int row = f >> 3, cs = f & 7;
            float4 val = *(const float4*)(W + (size_t)(h*64 + row) * CDIM + c0 + cs * 4);
            Bs[cs*4+0][row] = val.x; Bs[cs*4+1][row] = val.y;
            Bs[cs*4+2][row] = val.z; Bs[cs*4+3][row] = val.w;
        }
        __syncthreads();
        #pragma unroll 8
        for (int kk = 0; kk < 32; kk++) {
            float4 a0 = *(const float4*)&As[kk][ty*8];
            float4 a1 = *(const float4*)&As[kk][ty*8+4];
            float4 b  = *(const float4*)&Bs[kk][tx*4];
            float av_[8] = {a0.x,a0.y,a0.z,a0.w,a1.x,a1.y,a1.z,a1.w};
            float bv[4]  = {b.x,b.y,b.z,b.w};
            #pragma unroll
            for (int i = 0; i < 8; i++)
                #pragma unroll
                for (int j = 0; j < 4; j++) acc[i][j] += av_[i] * bv[j];
        }
        __syncthreads();
    }
    #pragma unroll
    for (int i = 0; i < 8; i++) {
        int m = m0 + ty*8 + i;
        int b = m >> 11, tt = m & 2047;
        float* op = out + (((size_t)(b*NH + h) * T_SEQ + tt) * DH + tx*4);
        float4 r = {acc[i][0], acc[i][1], acc[i][2], acc[i][3]};
        *(float4*)op = r;
    }
}

// ---------------------------------------------------------------------------
// Kernel 2: RoPE in-place on q and k (first 32 of 64 dims).
// out[d]    = u[d]*cos(t*f_d)    - u[d+16]*sin(t*f_d)      (d < 16)
// out[d+16] = u[d+16]*cos(t*f_e) + u[d]*sin(t*f_e)         (e = d+16)
// ---------------------------------------------------------------------------
__global__ __launch_bounds__(256) void rope_kernel(float* __restrict__ q,
                                                   float* __restrict__ k)
{
    int idx = blockIdx.x * 256 + threadIdx.x;
    const int half_total = BSZ * NH * T_SEQ * 16;
    float* buf = (idx < half_total) ? q : k;
    int id2 = (idx < half_total) ? idx : idx - half_total;
    int d = id2 & 15;
    int row = id2 >> 4;           // (b*H + h)*T + t
    float* p = buf + (size_t)row * DH;
    float u0 = p[d], u1 = p[d + 16];
    float tf = (float)(row & (T_SEQ - 1));
    float f0 = __expf(-(float)d * LOG10000_32);
    float f1 = __expf(-(float)(d + 16) * LOG10000_32);
    float s0, c0, s1, c1;
    sincosf(tf * f0, &s0, &c0);
    sincosf(tf * f1, &s1, &c1);
    p[d]      = u0 * c0 - u1 * s0;
    p[d + 16] = u1 * c1 + u0 * s1;
}

// ---------------------------------------------------------------------------
// Kernel 3: raw scores.  att[z][i][j] = (q_i . k_j)*scale + bias[i-j+2047, h]
// BM=128 (i), BN=64 (j), BK=64 = full D, single K step.  Causal tile skip.
// Masked (j>i) positions get garbage-but-finite values; softmax ignores them.
// ---------------------------------------------------------------------------
__global__ __launch_bounds__(256) void scores_kernel(
    const float* __restrict__ q, const float* __restrict__ k,
    const float* __restrict__ rel_bias, float* __restrict__ att)
{
    const int bx = blockIdx.x;           // i tile (128)
    const int by = blockIdx.y;           // j tile (64)
    if (by > 2 * bx + 1) return;         // fully-masked tile
    const int z = blockIdx.z;            // b*H + h
    const int h = z % NH;

    __shared__ float Qs[64][132];
    __shared__ float Ks[64][68];

    const int tid = threadIdx.x;
    const int tx = tid & 15, ty = tid >> 4;
    const int i0 = bx * 128, j0 = by * 64;
    const float* qb = q + (size_t)z * T_SEQ * DH;
    const float* kb = k + (size_t)z * T_SEQ * DH;

    #pragma unroll
    for (int u = 0; u < 8; u++) {                    // Q tile 128x64
        int f = tid + 256 * u;                       // 0..2047 float4s
        int row = f >> 4, ds = f & 15;
        float4 val = *(const float4*)(qb + (size_t)(i0 + row) * DH + ds * 4);
        Qs[ds*4+0][row] = val.x; Qs[ds*4+1][row] = val.y;
        Qs[ds*4+2][row] = val.z; Qs[ds*4+3][row] = val.w;
    }
    #pragma unroll
    for (int u = 0; u < 4; u++) {                    // K tile 64x64
        int f = tid + 256 * u;                       // 0..1023
        int row = f >> 4, ds = f & 15;
        float4 val = *(const float4*)(kb + (size_t)(j0 + row) * DH + ds * 4);
        Ks[ds*4+0][row] = val.x; Ks[ds*4+1][row] = val.y;
        Ks[ds*4+2][row] = val.z; Ks[ds*4+3][row] = val.w;
    }
    __syncthreads();

    float acc[8][4];
    #pragma unroll
    for (int i = 0; i < 8; i++)
        #pragma unroll
        for (int j = 0; j < 4; j++) acc[i][j] = 0.f;

    #pragma unroll 8
    for (int kk = 0; kk < 64; kk++) {
        float4 a0 = *(const float4*)&Qs[kk][ty*8];
        float4 a1 = *(const float4*)&Qs[kk][ty*8+4];
        float4 b  = *(const float4*)&Ks[kk][tx*4];
        float av_[8] = {a0.x,a0.y,a0.z,a0.w,a1.x,a1.y,a1.z,a1.w};
        float bv[4]  = {b.x,b.y,b.z,b.w};
        #pragma unroll
        for (int i = 0; i < 8; i++)
            #pragma unroll
            for (int j = 0; j < 4; j++) acc[i][j] += av_[i] * bv[j];
    }

    #pragma unroll
    for (int i = 0; i < 8; i++) {
        int i_g = i0 + ty*8 + i;
        float* op = att + ((size_t)z * T_SEQ + i_g) * T_SEQ + j0 + tx*4;
        float4 r;
        float* rr = (float*)&r;
        #pragma unroll
        for (int j = 0; j < 4; j++) {
            int j_g = j0 + tx*4 + j;
            int coord = i_g - j_g + (T_SEQ - 1);
            rr[j] = acc[i][j] * SCALE + rel_bias[(size_t)coord * NH + h];
        }
        *(float4*)op = r;
    }
}

// ---------------------------------------------------------------------------
// Kernel 4: row softmax over att, one wave (64 lanes) per row, row resident
// in 8 float4/lane.  Valid length L = i+1; cols > i written as exact 0.
// ---------------------------------------------------------------------------
__global__ __launch_bounds__(256) void softmax_kernel(float* __restrict__ att)
{
    int gtid = blockIdx.x * 256 + threadIdx.x;
    int wave = gtid >> 6;
    int lane = threadIdx.x & 63;
    if (wave >= BSZ * NH * T_SEQ) return;
    int z = wave >> 11, i = wave & (T_SEQ - 1);
    float* row = att + ((size_t)z * T_SEQ + i) * T_SEQ;
    const int L = i + 1;

    float4 vals[8];
    float m = -INFINITY;
    #pragma unroll
    for (int it = 0; it < 8; ++it) {
        int c0 = it * 256 + lane * 4;
        float4 v = {-INFINITY, -INFINITY, -INFINITY, -INFINITY};
        if (c0 < L) {
            v = *(const float4*)(row + c0);
            if (c0 + 1 >= L) v.y = -INFINITY;
            if (c0 + 2 >= L) v.z = -INFINITY;
            if (c0 + 3 >= L) v.w = -INFINITY;
        }
        vals[it] = v;
        m = fmaxf(m, fmaxf(fmaxf(v.x, v.y), fmaxf(v.z, v.w)));
    }
    #pragma unroll
    for (int off = 32; off >= 1; off >>= 1) m = fmaxf(m, __shfl_xor(m, off));

    float s = 0.f;
    #pragma unroll
    for (int it = 0; it < 8; ++it) {
        float4 v = vals[it];
        v.x = __expf(v.x - m); v.y = __expf(v.y - m);
        v.z = __expf(v.z - m); v.w = __expf(v.w - m);
        vals[it] = v;
        s += v.x + v.y + v.z + v.w;
    }
    #pragma unroll
    for (int off = 32; off >= 1; off >>= 1) s += __shfl_xor(s, off);
    float inv = 1.f / s;

    #pragma unroll
    for (int it = 0; it < 8; ++it) {
        int c0 = it * 256 + lane * 4;
        float4 v = vals[it];
        v.x *= inv; v.y *= inv; v.z *= inv; v.w *= inv;
        *(float4*)(row + c0) = v;
    }
}

// ---------------------------------------------------------------------------
// Kernel 5: y_att = att @ v  (NN GEMM, causal-capped K).  BM=64, BN=64(=D),
// BK=32, 4x4 per thread.  Output to ypre in (b, t, h*64+d) layout.
// ---------------------------------------------------------------------------
__global__ __launch_bounds__(256) void av_kernel(
    const float* __restrict__ att, const float* __restrict__ v,
    float* __restrict__ ypre)
{
    const int bx = blockIdx.x;           // i tile (64)
    const int z = blockIdx.z;
    const int h = z % NH, b = z / NH;
    __shared__ float As[32][68];
    __shared__ float Bs[32][68];
    const int tid = threadIdx.x;
    const int tx = tid & 15, ty = tid >> 4;
    const int m0 = bx * 64;
    const float* ab = att + (size_t)z * T_SEQ * T_SEQ;
    const float* vb = v + (size_t)z * T_SEQ * DH;

    float acc[4][4];
    #pragma unroll
    for (int i = 0; i < 4; i++)
        #pragma unroll
        for (int j = 0; j < 4; j++) acc[i][j] = 0.f;

    const int kmax = m0 + 64;            // j <= i < m0+64
    for (int k0 = 0; k0 < kmax; k0 += 32) {
        #pragma unroll
        for (int u = 0; u < 2; u++) {                // att tile 64x32 -> As[kk][m]
            int f = tid + 256 * u;                   // 0..511
            int row = f >> 3, cs = f & 7;
            float4 val = *(const float4*)(ab + (size_t)(m0 + row) * T_SEQ + k0 + cs * 4);
            As[cs*4+0][row] = val.x; As[cs*4+1][row] = val.y;
            As[cs*4+2][row] = val.z; As[cs*4+3][row] = val.w;
        }
        #pragma unroll
        for (int u = 0; u < 2; u++) {                // v tile 32x64 -> Bs[kk][n]
            int f = tid + 256 * u;                   // 0..511
            int row = f >> 4, ns = f & 15;
            float4 val = *(const float4*)(vb + (size_t)(k0 + row) * DH + ns * 4);
            *(float4*)&Bs[row][ns*4] = val;
        }
        __syncthreads();
        #pragma unroll 8
        for (int kk = 0; kk < 32; kk++) {
            float4 a  = *(const float4*)&As[kk][ty*4];
            float4 bv = *(const float4*)&Bs[kk][tx*4];
            float av_[4] = {a.x,a.y,a.z,a.w};
            float bvv[4] = {bv.x,bv.y,bv.z,bv.w};
            #pragma unroll
            for (int i = 0; i < 4; i++)
                #pragma unroll
                for (int j = 0; j < 4; j++) acc[i][j] += av_[i] * bvv[j];
        }
        __syncthreads();
    }
    #pragma unroll
    for (int i = 0; i < 4; i++) {
        int i_g = m0 + ty*4 + i;
        float* op = ypre + ((size_t)(b * T_SEQ) + i_g) * CDIM + h * DH + tx*4;
        float4 r = {acc[i][0], acc[i][1], acc[i][2], acc[i][3]};
        *(float4*)op = r;
    }
}

// ---------------------------------------------------------------------------
// Kernel 6: output projection.  y[m][n] = sum_c ypre[m][c]*Wp[n][c] + bp[n]
// Same structure as kernel 1; writes d_out y region row-major.
// ---------------------------------------------------------------------------
__global__ __launch_bounds__(256) void outproj_kernel(
    const float* __restrict__ ypre, const float* __restrict__ Wp,
    const float* __restrict__ bp, float* __restrict__ y)
{
    __shared__ float As[32][132];
    __shared__ float Bs[32][68];
    const int tid = threadIdx.x;
    const int tx = tid & 15, ty = tid >> 4;
    const int m0 = blockIdx.x * 128;
    const int n0 = blockIdx.y * 64;

    float acc[8][4];
    #pragma unroll
    for (int i = 0; i < 8; i++)
        #pragma unroll
        for (int j = 0; j < 4; j++) acc[i][j] = 0.f;

    for (int c0 = 0; c0 < CDIM; c0 += 32) {
        #pragma unroll
        for (int u = 0; u < 4; u++) {
            int f = tid + 256 * u;
            int row = f >> 3, cs = f & 7;
            float4 val = *(const float4*)(ypre + (size_t)(m0 + row) * CDIM + c0 + cs * 4);
            As[cs*4+0][row] = val.x; As[cs*4+1][row] = val.y;
            As[cs*4+2][row] = val.z; As[cs*4+3][row] = val.w;
        }
        #pragma unroll
        for (int u = 0; u < 2; u++) {
            int f = tid + 256 * u;
            int row = f >> 3, cs = f & 7;
            float4 val = *(const float4*)(Wp + (size_t)(n0 + row) * CDIM + c0 + cs * 4);
            Bs[cs*4+0][row] = val.x; Bs[cs*4+1][row] = val.y;
            Bs[cs*4+2][row] = val.z; Bs[cs*4+3][row] = val.w;
        }
        __syncthreads();
        #pragma unroll 8
        for (int kk = 0; kk < 32; kk++) {
            float4 a0 = *(const float4*)&As[kk][ty*8];
            float4 a1 = *(const float4*)&As[kk][ty*8+4];
            float4 b  = *(const float4*)&Bs[kk][tx*4];
            float av_[8] = {a0.x,a0.y,a0.z,a0.w,a1.x,a1.y,a1.z,a1.w};
            float bv[4]  = {b.x,b.y,b.z,b.w};
            #pragma unroll
            for (int i = 0; i < 8; i++)
                #pragma unroll
                for (int j = 0; j < 4; j++) acc[i][j] += av_[i] * bv[j];
        }
        __syncthreads();
    }
    float4 bias = *(const float4*)(bp + n0 + tx*4);
    float bb[4] = {bias.x, bias.y, bias.z, bias.w};
    #pragma unroll
    for (int i = 0; i < 8; i++) {
        int m = m0 + ty*8 + i;
        float* op = y + (size_t)m * CDIM + n0 + tx*4;
        float4 r = {acc[i][0] + bb[0], acc[i][1] + bb[1],
                    acc[i][2] + bb[2], acc[i][3] + bb[3]};
        *(float4*)op = r;
    }
}

// ---------------------------------------------------------------------------
extern "C" void kernel_launch(void* const* d_in, const int* in_sizes, int n_in,
                              void* d_out, int out_size, void* d_ws, size_t ws_size,
                              hipStream_t stream)
{
    const float* x        = (const float*)d_in[0];
    const float* Wq       = (const float*)d_in[1];
    const float* Wk       = (const float*)d_in[2];
    const float* Wv       = (const float*)d_in[3];
    const float* Wp       = (const float*)d_in[4];
    const float* bp       = (const float*)d_in[5];
    const float* rel_bias = (const float*)d_in[6];

    float* y   = (float*)d_out;                               // 4096*768
    float* att = y + (size_t)BSZ * T_SEQ * CDIM;              // 24*2048*2048

    // Workspace: q, k, v each B*H*T*D = 3,145,728 f32; ypre reuses q.
    float* q = (float*)d_ws;
    float* k = q + (size_t)3145728;
    float* v = k + (size_t)3145728;
    float* ypre = q;   // q dead after scores_kernel

    qkv_proj_kernel<<<dim3(32, 12, 3), 256, 0, stream>>>(x, Wq, Wk, Wv, q, k, v);
    rope_kernel<<<dim3(2 * BSZ * NH * T_SEQ * 16 / 256), 256, 0, stream>>>(q, k);
    scores_kernel<<<dim3(16, 32, BSZ * NH), 256, 0, stream>>>(q, k, rel_bias, att);
    softmax_kernel<<<dim3(BSZ * NH * T_SEQ * 64 / 256), 256, 0, stream>>>(att);
    av_kernel<<<dim3(32, 1, BSZ * NH), 256, 0, stream>>>(att, v, ypre);
    outproj_kernel<<<dim3(32, 12, 1), 256, 0, stream>>>(ypre, Wp, bp, y);
}

// Round 2
// 792.036 us; speedup vs baseline: 1.5510x; 1.5510x over previous
//
#include <hip/hip_runtime.h>
#include <math.h>

#define T_SEQ 2048
#define NH 12
#define DH 64
#define CDIM 768
#define BSZ 2
#define NZ (BSZ*NH)                      // 24
#define SCALE 0.125f
#define LOG10000_32 0.2878231366242557f  // ln(10000)/32

typedef short bf16x8 __attribute__((ext_vector_type(8)));
typedef float f32x4 __attribute__((ext_vector_type(4)));

static __device__ inline short f2bf(float f) {
    unsigned u = __float_as_uint(f);
    unsigned r = (u + 0x7FFF + ((u >> 16) & 1)) >> 16;   // RNE
    return (short)r;
}

// ---------------------------------------------------------------------------
// f32 -> bf16 copy (vectorized x4)
// ---------------------------------------------------------------------------
__global__ __launch_bounds__(256) void convert_kernel(
    const float* __restrict__ s, short* __restrict__ d, int n4)
{
    int i = blockIdx.x * 256 + threadIdx.x;
    if (i >= n4) return;
    float4 v = ((const float4*)s)[i];
    short4 o = { f2bf(v.x), f2bf(v.y), f2bf(v.z), f2bf(v.w) };
    ((short4*)d)[i] = o;
}

// ---------------------------------------------------------------------------
// Fused QKV projection, bf16 MFMA.  A = xb [4096][768], B = Wqkv [2304][768]
// (rows 0..767 Wq, 768..1535 Wk, 1536..2303 Wv).  Tile 128x128, BK=32,
// 4 waves each computing 64x64 via 4x4 mfma_16x16x32 fragments.
// q,k written f32 (b,h,t,d) for RoPE; v written bf16 (b,h,d,t) [d-major!].
// ---------------------------------------------------------------------------
__global__ __launch_bounds__(256) void qkv_mfma(
    const short* __restrict__ A, const short* __restrict__ B,
    float* __restrict__ q, float* __restrict__ k, short* __restrict__ v)
{
    __shared__ short As[128][40];   // stride 40 bf16 = 80B: 2-way max on b128
    __shared__ short Bs[128][40];
    const int tid = threadIdx.x;
    const int lane = tid & 63, w = tid >> 6;
    const int wm = (w >> 1) * 64, wn = (w & 1) * 64;
    const int lr = lane & 15, lg = lane >> 4;
    const int m0 = blockIdx.x * 128, n0 = blockIdx.y * 128;

    f32x4 acc[4][4];
    #pragma unroll
    for (int i = 0; i < 4; i++)
        #pragma unroll
        for (int j = 0; j < 4; j++)
            #pragma unroll
            for (int r = 0; r < 4; r++) acc[i][j][r] = 0.f;

    const int srow = tid >> 2, schunk = tid & 3;
    for (int c0 = 0; c0 < CDIM; c0 += 32) {
        #pragma unroll
        for (int u = 0; u < 2; u++) {
            int row = srow + u * 64;
            *(float4*)&As[row][schunk * 8] =
                *(const float4*)&A[(size_t)(m0 + row) * CDIM + c0 + schunk * 8];
            *(float4*)&Bs[row][schunk * 8] =
                *(const float4*)&B[(size_t)(n0 + row) * CDIM + c0 + schunk * 8];
        }
        __syncthreads();
        bf16x8 af[4], bfr[4];
        #pragma unroll
        for (int f = 0; f < 4; f++) {
            af[f]  = *(const bf16x8*)&As[wm + f * 16 + lr][lg * 8];
            bfr[f] = *(const bf16x8*)&Bs[wn + f * 16 + lr][lg * 8];
        }
        #pragma unroll
        for (int i = 0; i < 4; i++)
            #pragma unroll
            for (int j = 0; j < 4; j++)
                acc[i][j] = __builtin_amdgcn_mfma_f32_16x16x32_bf16(
                    af[i], bfr[j], acc[i][j], 0, 0, 0);
        __syncthreads();
    }

    const int which = n0 / CDIM;          // 0=q 1=k 2=v (tiles never straddle)
    const int nbase = n0 - which * CDIM;
    #pragma unroll
    for (int i = 0; i < 4; i++) {
        #pragma unroll
        for (int r = 0; r < 4; r++) {
            int gm = m0 + wm + i * 16 + lg * 4 + r;   // b*2048 + t
            int b = gm >> 11, t = gm & 2047;
            #pragma unroll
            for (int j = 0; j < 4; j++) {
                int nc = nbase + wn + j * 16 + lr;    // h*64 + d
                int h = nc >> 6, d = nc & 63;
                float val = acc[i][j][r];
                if (which == 0)
                    q[(((size_t)(b * NH + h) * T_SEQ + t) * DH) + d] = val;
                else if (which == 1)
                    k[(((size_t)(b * NH + h) * T_SEQ + t) * DH) + d] = val;
                else  // v stored d-major: [z][d][t]
                    v[(((size_t)(b * NH + h) * DH + d) * T_SEQ) + t] = f2bf(val);
            }
        }
    }
}

// ---------------------------------------------------------------------------
// RoPE: read q,k f32 (b,h,t,d), write qb,kb bf16 same layout.
// Thread handles (row, d<16): elems d, d+16 rotated; d+32, d+48 copied.
// ---------------------------------------------------------------------------
__global__ __launch_bounds__(256) void rope_bf16(
    const float* __restrict__ q, const float* __restrict__ k,
    short* __restrict__ qb, short* __restrict__ kb)
{
    int idx = blockIdx.x * 256 + threadIdx.x;
    const int half_total = NZ * T_SEQ * 16;
    const float* src = (idx < half_total) ? q : k;
    short* dst = (idx < half_total) ? qb : kb;
    int id2 = (idx < half_total) ? idx : idx - half_total;
    int d = id2 & 15, row = id2 >> 4;     // row = z*T + t
    const float* p = src + (size_t)row * DH;
    short* o = dst + (size_t)row * DH;
    float u0 = p[d], u1 = p[d + 16], u2 = p[d + 32], u3 = p[d + 48];
    float tf = (float)(row & (T_SEQ - 1));
    float f0 = __expf(-(float)d * LOG10000_32);
    float f1 = __expf(-(float)(d + 16) * LOG10000_32);
    float s0, c0, s1, c1;
    sincosf(tf * f0, &s0, &c0);
    sincosf(tf * f1, &s1, &c1);
    o[d]      = f2bf(u0 * c0 - u1 * s0);
    o[d + 16] = f2bf(u1 * c1 + u0 * s1);
    o[d + 32] = f2bf(u2);
    o[d + 48] = f2bf(u3);
}

// ---------------------------------------------------------------------------
// Scores: S = Q.K^T * scale + rel_bias, bf16 MFMA, tile 128x128, K=64 single
// staging step (2 MFMA k-steps).  Causal tile skip (tj > ti).  Bias row
// staged in LDS (255 entries indexed by di-dj+127).  f32 out to att.
// ---------------------------------------------------------------------------
__global__ __launch_bounds__(256) void scores_mfma(
    const short* __restrict__ qb, const short* __restrict__ kb,
    const float* __restrict__ rel_bias, float* __restrict__ att)
{
    const int ti = blockIdx.x, tj = blockIdx.y;
    if (tj > ti) return;
    const int z = blockIdx.z;
    const int h = z % NH;
    __shared__ short Qs[128][72];   // 64 data + 8 pad: 2-way max
    __shared__ short Ks[128][72];
    __shared__ float bias_s[256];
    const int tid = threadIdx.x;
    const int lane = tid & 63, w = tid >> 6;
    const int wm = (w >> 1) * 64, wn = (w & 1) * 64;
    const int lr = lane & 15, lg = lane >> 4;
    const int i0 = ti * 128, j0 = tj * 128;
    const short* qz = qb + (size_t)z * T_SEQ * DH;
    const short* kz = kb + (size_t)z * T_SEQ * DH;

    {
        int row = tid >> 3, chunk = tid & 7;
        #pragma unroll
        for (int u = 0; u < 4; u++) {
            int r = row + u * 32;
            *(float4*)&Qs[r][chunk * 8] =
                *(const float4*)&qz[(size_t)(i0 + r) * DH + chunk * 8];
            *(float4*)&Ks[r][chunk * 8] =
                *(const float4*)&kz[(size_t)(j0 + r) * DH + chunk * 8];
        }
    }
    if (tid < 255)
        bias_s[tid] = rel_bias[(size_t)(i0 - j0 + 1920 + tid) * NH + h];
    __syncthreads();

    f32x4 acc[4][4];
    #pragma unroll
    for (int i = 0; i < 4; i++)
        #pragma unroll
        for (int j = 0; j < 4; j++)
            #pragma unroll
            for (int r = 0; r < 4; r++) acc[i][j][r] = 0.f;

    #pragma unroll
    for (int kh = 0; kh < 2; kh++) {
        bf16x8 af[4], bfr[4];
        #pragma unroll
        for (int f = 0; f < 4; f++) {
            af[f]  = *(const bf16x8*)&Qs[wm + f * 16 + lr][kh * 32 + lg * 8];
            bfr[f] = *(const bf16x8*)&Ks[wn + f * 16 + lr][kh * 32 + lg * 8];
        }
        #pragma unroll
        for (int i = 0; i < 4; i++)
            #pragma unroll
            for (int j = 0; j < 4; j++)
                acc[i][j] = __builtin_amdgcn_mfma_f32_16x16x32_bf16(
                    af[i], bfr[j], acc[i][j], 0, 0, 0);
    }

    #pragma unroll
    for (int i = 0; i < 4; i++) {
        #pragma unroll
        for (int r = 0; r < 4; r++) {
            int di = wm + i * 16 + lg * 4 + r;
            float* orow = att + ((size_t)z * T_SEQ + i0 + di) * T_SEQ + j0;
            #pragma unroll
            for (int j = 0; j < 4; j++) {
                int dj = wn + j * 16 + lr;
                orow[dj] = acc[i][j][r] * SCALE + bias_s[di - dj + 127];
            }
        }
    }
}

// ---------------------------------------------------------------------------
// Row softmax, one wave per row, row in registers.  Writes exact 0 past L.
// ---------------------------------------------------------------------------
__global__ __launch_bounds__(256) void softmax_kernel(float* __restrict__ att)
{
    int gtid = blockIdx.x * 256 + threadIdx.x;
    int wave = gtid >> 6;
    int lane = threadIdx.x & 63;
    if (wave >= NZ * T_SEQ) return;
    int z = wave >> 11, i = wave & (T_SEQ - 1);
    float* row = att + ((size_t)z * T_SEQ + i) * T_SEQ;
    const int L = i + 1;

    float4 vals[8];
    float m = -INFINITY;
    #pragma unroll
    for (int it = 0; it < 8; ++it) {
        int c0 = it * 256 + lane * 4;
        float4 v = {-INFINITY, -INFINITY, -INFINITY, -INFINITY};
        if (c0 < L) {
            v = *(const float4*)(row + c0);
            if (c0 + 1 >= L) v.y = -INFINITY;
            if (c0 + 2 >= L) v.z = -INFINITY;
            if (c0 + 3 >= L) v.w = -INFINITY;
        }
        vals[it] = v;
        m = fmaxf(m, fmaxf(fmaxf(v.x, v.y), fmaxf(v.z, v.w)));
    }
    #pragma unroll
    for (int off = 32; off >= 1; off >>= 1) m = fmaxf(m, __shfl_xor(m, off));

    float s = 0.f;
    #pragma unroll
    for (int it = 0; it < 8; ++it) {
        float4 v = vals[it];
        v.x = __expf(v.x - m); v.y = __expf(v.y - m);
        v.z = __expf(v.z - m); v.w = __expf(v.w - m);
        vals[it] = v;
        s += v.x + v.y + v.z + v.w;
    }
    #pragma unroll
    for (int off = 32; off >= 1; off >>= 1) s += __shfl_xor(s, off);
    float inv = 1.f / s;

    #pragma unroll
    for (int it = 0; it < 8; ++it) {
        int c0 = it * 256 + lane * 4;
        float4 v = vals[it];
        v.x *= inv; v.y *= inv; v.z *= inv; v.w *= inv;
        *(float4*)(row + c0) = v;
    }
}

// ---------------------------------------------------------------------------
// y_att = att @ v.  att f32 converted to bf16 while staging; v is d-major
// bf16 [z][d][t] so the (col=d, k=t) LDS tile stages contiguously.
// Tile: 128 rows x 64 cols, BK=64, 4 waves each 32x64 (2x4 frags).
// Output ypre bf16 [4096][768].
// ---------------------------------------------------------------------------
__global__ __launch_bounds__(256) void av_mfma(
    const float* __restrict__ att, const short* __restrict__ vb,
    short* __restrict__ ypre)
{
    const int ti = blockIdx.x, z = blockIdx.y;
    const int h = z % NH, b = z / NH;
    __shared__ short Ps[128][72];
    __shared__ short Vs[64][72];    // Vs[d][k]
    const int tid = threadIdx.x;
    const int lane = tid & 63, w = tid >> 6;
    const int wm = w * 32;
    const int lr = lane & 15, lg = lane >> 4;
    const int i0 = ti * 128;
    const float* az = att + (size_t)z * T_SEQ * T_SEQ;
    const short* vz = vb + (size_t)z * DH * T_SEQ;

    f32x4 acc[2][4];
    #pragma unroll
    for (int i = 0; i < 2; i++)
        #pragma unroll
        for (int j = 0; j < 4; j++)
            #pragma unroll
            for (int r = 0; r < 4; r++) acc[i][j][r] = 0.f;

    const int kmax = i0 + 128;
    const int prow = tid >> 4, pfc = tid & 15;
    const int vrow = tid >> 3, vchunk = tid & 7;
    for (int k0 = 0; k0 < kmax; k0 += 64) {
        #pragma unroll
        for (int u = 0; u < 8; u++) {             // P: 128x64 f32 -> bf16
            int r = prow + u * 16;
            float4 pv = *(const float4*)&az[(size_t)(i0 + r) * T_SEQ + k0 + pfc * 4];
            short4 o = { f2bf(pv.x), f2bf(pv.y), f2bf(pv.z), f2bf(pv.w) };
            *(short4*)&Ps[r][pfc * 4] = o;
        }
        #pragma unroll
        for (int u = 0; u < 2; u++) {             // V: 64(d) x 64(k) bf16
            int r = vrow + u * 32;
            *(float4*)&Vs[r][vchunk * 8] =
                *(const float4*)&vz[(size_t)r * T_SEQ + k0 + vchunk * 8];
        }
        __syncthreads();
        #pragma unroll
        for (int kh = 0; kh < 2; kh++) {
            bf16x8 pf[2], vf[4];
            #pragma unroll
            for (int i = 0; i < 2; i++)
                pf[i] = *(const bf16x8*)&Ps[wm + i * 16 + lr][kh * 32 + lg * 8];
            #pragma unroll
            for (int j = 0; j < 4; j++)
                vf[j] = *(const bf16x8*)&Vs[j * 16 + lr][kh * 32 + lg * 8];
            #pragma unroll
            for (int i = 0; i < 2; i++)
                #pragma unroll
                for (int j = 0; j < 4; j++)
                    acc[i][j] = __builtin_amdgcn_mfma_f32_16x16x32_bf16(
                        pf[i], vf[j], acc[i][j], 0, 0, 0);
        }
        __syncthreads();
    }

    #pragma unroll
    for (int i = 0; i < 2; i++) {
        #pragma unroll
        for (int r = 0; r < 4; r++) {
            int gi = i0 + wm + i * 16 + lg * 4 + r;
            short* orow = ypre + ((size_t)(b * T_SEQ) + gi) * CDIM + h * DH;
            #pragma unroll
            for (int j = 0; j < 4; j++) {
                int dj = j * 16 + lr;
                orow[dj] = f2bf(acc[i][j][r]);
            }
        }
    }
}

// ---------------------------------------------------------------------------
// Output projection: y = ypre @ Wp^T + bp.  Same structure as qkv_mfma.
// ---------------------------------------------------------------------------
__global__ __launch_bounds__(256) void outproj_mfma(
    const short* __restrict__ A, const short* __restrict__ B,
    const float* __restrict__ bp, float* __restrict__ y)
{
    __shared__ short As[128][40];
    __shared__ short Bs[128][40];
    const int tid = threadIdx.x;
    const int lane = tid & 63, w = tid >> 6;
    const int wm = (w >> 1) * 64, wn = (w & 1) * 64;
    const int lr = lane & 15, lg = lane >> 4;
    const int m0 = blockIdx.x * 128, n0 = blockIdx.y * 128;

    f32x4 acc[4][4];
    #pragma unroll
    for (int i = 0; i < 4; i++)
        #pragma unroll
        for (int j = 0; j < 4; j++)
            #pragma unroll
            for (int r = 0; r < 4; r++) acc[i][j][r] = 0.f;

    const int srow = tid >> 2, schunk = tid & 3;
    for (int c0 = 0; c0 < CDIM; c0 += 32) {
        #pragma unroll
        for (int u = 0; u < 2; u++) {
            int row = srow + u * 64;
            *(float4*)&As[row][schunk * 8] =
                *(const float4*)&A[(size_t)(m0 + row) * CDIM + c0 + schunk * 8];
            *(float4*)&Bs[row][schunk * 8] =
                *(const float4*)&B[(size_t)(n0 + row) * CDIM + c0 + schunk * 8];
        }
        __syncthreads();
        bf16x8 af[4], bfr[4];
        #pragma unroll
        for (int f = 0; f < 4; f++) {
            af[f]  = *(const bf16x8*)&As[wm + f * 16 + lr][lg * 8];
            bfr[f] = *(const bf16x8*)&Bs[wn + f * 16 + lr][lg * 8];
        }
        #pragma unroll
        for (int i = 0; i < 4; i++)
            #pragma unroll
            for (int j = 0; j < 4; j++)
                acc[i][j] = __builtin_amdgcn_mfma_f32_16x16x32_bf16(
                    af[i], bfr[j], acc[i][j], 0, 0, 0);
        __syncthreads();
    }

    #pragma unroll
    for (int i = 0; i < 4; i++) {
        #pragma unroll
        for (int r = 0; r < 4; r++) {
            int gm = m0 + wm + i * 16 + lg * 4 + r;
            float* orow = y + (size_t)gm * CDIM + n0;
            #pragma unroll
            for (int j = 0; j < 4; j++) {
                int gn = wn + j * 16 + lr;
                orow[gn] = acc[i][j][r] + bp[n0 + gn];
            }
        }
    }
}

// ---------------------------------------------------------------------------
extern "C" void kernel_launch(void* const* d_in, const int* in_sizes, int n_in,
                              void* d_out, int out_size, void* d_ws, size_t ws_size,
                              hipStream_t stream)
{
    const float* x        = (const float*)d_in[0];
    const float* Wq       = (const float*)d_in[1];
    const float* Wk       = (const float*)d_in[2];
    const float* Wv       = (const float*)d_in[3];
    const float* Wp       = (const float*)d_in[4];
    const float* bp       = (const float*)d_in[5];
    const float* rel_bias = (const float*)d_in[6];

    float* y   = (float*)d_out;
    float* att = y + (size_t)BSZ * T_SEQ * CDIM;

    const size_t NE = (size_t)NZ * T_SEQ * DH;     // 3,145,728
    float* qf = (float*)d_ws;                      // 12.58 MB
    float* kf = qf + NE;                           // 12.58 MB
    short* vb = (short*)(kf + NE);                 //  6.29 MB (d-major)
    short* qb = vb + NE;                           //  6.29 MB
    short* kb = qb + NE;                           //  6.29 MB
    short* xb = kb + NE;                           //  6.29 MB
    short* wqkvb = xb + NE;                        //  3.54 MB
    short* wpb = wqkvb + (size_t)3 * CDIM * CDIM;  //  1.18 MB
    short* ypre = (short*)qf;                      //  reuse (qf dead post-rope)

    const int NW4 = CDIM * CDIM / 4;               // 147456
    convert_kernel<<<dim3(NE / 1024), 256, 0, stream>>>(x, xb, (int)(NE / 4));
    convert_kernel<<<dim3(NW4 / 256), 256, 0, stream>>>(Wq, wqkvb, NW4);
    convert_kernel<<<dim3(NW4 / 256), 256, 0, stream>>>(Wk, wqkvb + (size_t)CDIM * CDIM, NW4);
    convert_kernel<<<dim3(NW4 / 256), 256, 0, stream>>>(Wv, wqkvb + (size_t)2 * CDIM * CDIM, NW4);
    convert_kernel<<<dim3(NW4 / 256), 256, 0, stream>>>(Wp, wpb, NW4);

    qkv_mfma<<<dim3(32, 18), 256, 0, stream>>>(xb, wqkvb, qf, kf, vb);
    rope_bf16<<<dim3(2 * NZ * T_SEQ * 16 / 256), 256, 0, stream>>>(qf, kf, qb, kb);
    scores_mfma<<<dim3(16, 16, NZ), 256, 0, stream>>>(qb, kb, rel_bias, att);
    softmax_kernel<<<dim3(NZ * T_SEQ * 64 / 256), 256, 0, stream>>>(att);
    av_mfma<<<dim3(16, NZ), 256, 0, stream>>>(att, vb, ypre);
    outproj_mfma<<<dim3(32, 6), 256, 0, stream>>>(ypre, wpb, bp, y);
}